// Round 2
// baseline (265.119 us; speedup 1.0000x reference)
//
#include <hip/hip_runtime.h>

// IndRNN net, algebraically collapsed (verified exact, R1 absmax=0.0):
// predict uses only decoder-batch 0 => last[0] = y_enc1[t=0, b=4095] =>
// encoder needed only at (t=0, b=4095); recurrent u terms vanish at t=0.
// R2: fuse the 4-kernel chain into ONE persistent kernel with a monotone
// global barrier (agent-scope atomics) to kill 3 launch gaps.
// Grid 512x256 = 2 blocks/CU -- co-residency guaranteed by capacity
// (~60 VGPR, 5 KB LDS, 8 of 32 waves/CU).

#define HID 1024
#define TSTEPS 20
#define NBLK 512

__device__ __forceinline__ float wred64(float v) {
#pragma unroll
    for (int off = 32; off > 0; off >>= 1) v += __shfl_down(v, off, 64);
    return v;  // lane 0 holds the sum
}

// Monotone grid barrier #k (k = 1,2,3,...): arrive once, spin until all
// NBLK blocks have arrived k times. No reset => no ABA. bar zeroed by k_init.
__device__ __forceinline__ void gbar(int* bar, int k) {
    __syncthreads();
    if (threadIdx.x == 0) {
        __threadfence();  // publish this block's prior global writes
        __hip_atomic_fetch_add(bar, 1, __ATOMIC_RELEASE, __HIP_MEMORY_SCOPE_AGENT);
        while (__hip_atomic_load(bar, __ATOMIC_ACQUIRE, __HIP_MEMORY_SCOPE_AGENT) < NBLK * k)
            __builtin_amdgcn_s_sleep(1);
        __threadfence();  // acquire: see other blocks' writes
    }
    __syncthreads();
}

__global__ void k_init(int* bar) { *bar = 0; }

__global__ __launch_bounds__(256, 2) void k_fused(
    const float* __restrict__ x,
    const float* __restrict__ ew0, const float* __restrict__ eb0,
    const float* __restrict__ ew1, const float* __restrict__ eb1,
    const float* __restrict__ dw0, const float* __restrict__ du0,
    const float* __restrict__ db0,
    const float* __restrict__ dw1, const float* __restrict__ du1,
    const float* __restrict__ db1,
    const float* __restrict__ ow, const float* __restrict__ ob,
    float* __restrict__ out,
    float* __restrict__ last0, float* __restrict__ G, float* __restrict__ H1,
    int* __restrict__ bar)
{
    const int tid = threadIdx.x, b = blockIdx.x;
    const int wave = tid >> 6, lane = tid & 63;
    __shared__ float v0s[HID];
    __shared__ float red[8];
    __shared__ float ps[2];
    __shared__ float qs[2][TSTEPS];

    // ---- Phase 1: v0 = relu(ew0 @ x[0,4095] + eb0); last0 = relu(ew1 @ v0 + eb1)
    {
        const float x0 = x[8190], x1 = x[8191];
#pragma unroll
        for (int i = tid; i < HID; i += 256) {
            float2 w2 = ((const float2*)ew0)[i];
            v0s[i] = fmaxf(fmaf(w2.x, x0, fmaf(w2.y, x1, eb0[i])), 0.f);
        }
        __syncthreads();
#pragma unroll
        for (int rr = 0; rr < 2; ++rr) {
            const int r = b + rr * NBLK;
            float4 wv = ((const float4*)(ew1 + r * HID))[tid];
            float4 vv = ((const float4*)v0s)[tid];
            float s = wv.x * vv.x + wv.y * vv.y + wv.z * vv.z + wv.w * vv.w;
            s = wred64(s);
            if (lane == 0) red[wave] = s;
            __syncthreads();
            if (tid == 0)
                last0[r] = fmaxf(red[0] + red[1] + red[2] + red[3] + eb1[r], 0.f);
            __syncthreads();
        }
    }
    gbar(bar, 1);

    // ---- Phase 2: p = dw0 @ last0 + db0; G[t] = scan relu(p + u0*g)
    {
        float4 l4 = ((const float4*)last0)[tid];
#pragma unroll
        for (int rr = 0; rr < 2; ++rr) {
            const int r = b + rr * NBLK;
            float4 wv = ((const float4*)(dw0 + r * HID))[tid];
            float s = wv.x * l4.x + wv.y * l4.y + wv.z * l4.z + wv.w * l4.w;
            s = wred64(s);
            if (lane == 0) red[wave] = s;
            __syncthreads();
            if (tid == 0) ps[rr] = red[0] + red[1] + red[2] + red[3] + db0[r];
            __syncthreads();
        }
        if (tid < 2) {
            const int r = b + tid * NBLK;
            float p = ps[tid], uu = du0[r], g = 0.f;
#pragma unroll
            for (int t = 0; t < TSTEPS; ++t) {
                g = fmaxf(fmaf(uu, g, p), 0.f);
                G[t * HID + r] = g;
            }
        }
    }
    gbar(bar, 2);

    // ---- Phase 3: Q[t] = dw1 @ G[t] + db1; H1[t] = scan relu(q + u1*h)
    // Wave w handles t = w, w+4, ..., w+16 (5 sequential reductions/wave).
    {
#pragma unroll
        for (int rr = 0; rr < 2; ++rr) {
            const int r = b + rr * NBLK;
            const float4* wrow = (const float4*)(dw1 + r * HID);
            float4 w0v = wrow[lane * 4 + 0], w1v = wrow[lane * 4 + 1];
            float4 w2v = wrow[lane * 4 + 2], w3v = wrow[lane * 4 + 3];
            for (int t = wave; t < TSTEPS; t += 4) {
                const float4* gt = (const float4*)(G + t * HID);
                float4 g0 = gt[lane * 4 + 0], g1 = gt[lane * 4 + 1];
                float4 g2 = gt[lane * 4 + 2], g3 = gt[lane * 4 + 3];
                float s = w0v.x * g0.x + w0v.y * g0.y + w0v.z * g0.z + w0v.w * g0.w;
                s = fmaf(w1v.x, g1.x, s); s = fmaf(w1v.y, g1.y, s);
                s = fmaf(w1v.z, g1.z, s); s = fmaf(w1v.w, g1.w, s);
                s = fmaf(w2v.x, g2.x, s); s = fmaf(w2v.y, g2.y, s);
                s = fmaf(w2v.z, g2.z, s); s = fmaf(w2v.w, g2.w, s);
                s = fmaf(w3v.x, g3.x, s); s = fmaf(w3v.y, g3.y, s);
                s = fmaf(w3v.z, g3.z, s); s = fmaf(w3v.w, g3.w, s);
                s = wred64(s);
                if (lane == 0) qs[rr][t] = s;
            }
        }
        __syncthreads();
        if (tid < 2) {
            const int r = b + tid * NBLK;
            float uu = du1[r], bb = db1[r], hh = 0.f;
#pragma unroll
            for (int t = 0; t < TSTEPS; ++t) {
                hh = fmaxf(fmaf(uu, hh, qs[tid][t] + bb), 0.f);
                H1[t * HID + r] = hh;
            }
        }
    }
    gbar(bar, 3);

    // ---- Phase 4: predict[t] = ow @ H1[t] + ob  (blocks 0..19)
    if (b < TSTEPS) {
        const int t = b;
        float4 h4 = ((const float4*)(H1 + t * HID))[tid];
        float4 a4 = ((const float4*)ow)[tid];
        float4 b4 = ((const float4*)(ow + HID))[tid];
        float s0 = h4.x * a4.x + h4.y * a4.y + h4.z * a4.z + h4.w * a4.w;
        float s1 = h4.x * b4.x + h4.y * b4.y + h4.z * b4.z + h4.w * b4.w;
        s0 = wred64(s0);
        s1 = wred64(s1);
        if (lane == 0) { red[wave] = s0; red[4 + wave] = s1; }
        __syncthreads();
        if (tid == 0) out[2 * t + 0] = red[0] + red[1] + red[2] + red[3] + ob[0];
        if (tid == 1) out[2 * t + 1] = red[4] + red[5] + red[6] + red[7] + ob[1];
    }
}

extern "C" void kernel_launch(void* const* d_in, const int* in_sizes, int n_in,
                              void* d_out, int out_size, void* d_ws, size_t ws_size,
                              hipStream_t stream) {
    const float* x      = (const float*)d_in[0];
    const float* enc_w0 = (const float*)d_in[1];
    // d_in[2] = enc_u0 — provably unused (encoder only matters at t=0)
    const float* enc_b0 = (const float*)d_in[3];
    const float* enc_w1 = (const float*)d_in[4];
    // d_in[5] = enc_u1 — unused
    const float* enc_b1 = (const float*)d_in[6];
    const float* dec_w0 = (const float*)d_in[7];
    const float* dec_u0 = (const float*)d_in[8];
    const float* dec_b0 = (const float*)d_in[9];
    const float* dec_w1 = (const float*)d_in[10];
    const float* dec_u1 = (const float*)d_in[11];
    const float* dec_b1 = (const float*)d_in[12];
    const float* out_w  = (const float*)d_in[13];
    const float* out_b  = (const float*)d_in[14];
    float* out = (float*)d_out;

    float* ws    = (float*)d_ws;
    float* last0 = ws;                           // 1024
    float* G     = ws + HID;                     // 20*1024
    float* H1    = ws + HID + TSTEPS * HID;      // 20*1024
    int*   bar   = (int*)(ws + 64 * 1024);       // barrier counter (own line)

    k_init<<<1, 1, 0, stream>>>(bar);
    k_fused<<<NBLK, 256, 0, stream>>>(
        x, enc_w0, enc_b0, enc_w1, enc_b1,
        dec_w0, dec_u0, dec_b0, dec_w1, dec_u1, dec_b1,
        out_w, out_b, out, last0, G, H1, bar);
}

// Round 3
// 109.740 us; speedup vs baseline: 2.4159x; 2.4159x over previous
//
#include <hip/hip_runtime.h>

// IndRNN net, algebraically collapsed (verified exact, R1/R2 absmax=0.0):
// predict uses only decoder-batch 0 => last[0] = y_enc1[t=0, b=4095] =>
// encoder needed only at (t=0, b=4095); recurrent u terms vanish at t=0.
// R3: back to a launch chain (R2's persistent-kernel grid barrier cost
// ~60us/barrier from cross-XCD L2 writeback/invalidate). 3 kernels:
//   K1 enc (last0, init out with bias) -> K2 dec0 (G) -> K3 dec1+out proj
// K3 folds the output projection in as per-block partials + atomicAdd.

#define HID 1024
#define TSTEPS 20

__device__ __forceinline__ float wred64(float v) {
#pragma unroll
    for (int off = 32; off > 0; off >>= 1) v += __shfl_down(v, off, 64);
    return v;  // lane 0 holds the sum
}

// K1: v0 = relu(ew0 @ x[0,4095] + eb0); last0 = relu(ew1 @ v0 + eb1)
// Also seeds out[t][j] = ob[j] (K3 accumulates into it via atomicAdd).
__global__ __launch_bounds__(256) void k_enc(
    const float* __restrict__ x, const float* __restrict__ ew0,
    const float* __restrict__ eb0, const float* __restrict__ ew1,
    const float* __restrict__ eb1, const float* __restrict__ ob,
    float* __restrict__ last0, float* __restrict__ out) {
    const int tid = threadIdx.x, wave = tid >> 6, lane = tid & 63;
    __shared__ float v0s[HID];
    __shared__ float red[4];

    if (blockIdx.x == 0 && tid < 2 * TSTEPS) out[tid] = ob[tid & 1];

    const float x0 = x[8190], x1 = x[8191];  // x[t=0, b=4095, :]
#pragma unroll
    for (int i = tid; i < HID / 2; i += 256) {
        float4 w4 = ((const float4*)ew0)[i];   // rows 2i, 2i+1 (2 floats each)
        float2 e2 = ((const float2*)eb0)[i];
        v0s[2 * i + 0] = fmaxf(fmaf(w4.x, x0, fmaf(w4.y, x1, e2.x)), 0.f);
        v0s[2 * i + 1] = fmaxf(fmaf(w4.z, x0, fmaf(w4.w, x1, e2.y)), 0.f);
    }
    __syncthreads();

    const int r = blockIdx.x * 4 + wave;           // wave per output row
    const float4* wrow = (const float4*)(ew1 + r * HID);
    const float4* v4 = (const float4*)v0s;
    float s = 0.f;
#pragma unroll
    for (int k = 0; k < 4; ++k) {                   // contiguous 1KB/instr
        float4 w = wrow[k * 64 + lane], v = v4[k * 64 + lane];
        s = fmaf(w.x, v.x, s); s = fmaf(w.y, v.y, s);
        s = fmaf(w.z, v.z, s); s = fmaf(w.w, v.w, s);
    }
    s = wred64(s);
    if (lane == 0) last0[r] = fmaxf(s + eb1[r], 0.f);
}

// K2: p = dw0 @ last0 + db0; G[t][h] = scan relu(p + u0*g)
__global__ __launch_bounds__(256) void k_dec0(
    const float* __restrict__ last0, const float* __restrict__ dw0,
    const float* __restrict__ du0, const float* __restrict__ db0,
    float* __restrict__ G) {
    const int tid = threadIdx.x, wave = tid >> 6, lane = tid & 63;
    __shared__ float l0[HID];
    ((float4*)l0)[tid] = ((const float4*)last0)[tid];
    __syncthreads();

    const int r = blockIdx.x * 4 + wave;
    const float4* wrow = (const float4*)(dw0 + r * HID);
    const float4* v4 = (const float4*)l0;
    float s = 0.f;
#pragma unroll
    for (int k = 0; k < 4; ++k) {
        float4 w = wrow[k * 64 + lane], v = v4[k * 64 + lane];
        s = fmaf(w.x, v.x, s); s = fmaf(w.y, v.y, s);
        s = fmaf(w.z, v.z, s); s = fmaf(w.w, v.w, s);
    }
    s = wred64(s);
    if (lane == 0) {
        const float p = s + db0[r], uu = du0[r];
        float g = 0.f;
#pragma unroll
        for (int t = 0; t < TSTEPS; ++t) {
            g = fmaxf(fmaf(uu, g, p), 0.f);
            G[t * HID + r] = g;
        }
    }
}

// K3: Q[t] = dw1 @ G[t] + db1; H1[t] = scan relu(q + u1*h);
// out[t][j] += ow[j] . H1[t]  -- folded in as per-block partials + atomicAdd.
// 128 blocks x 256 thr; wave handles 2 rows (shares the G[t] loads).
__global__ __launch_bounds__(256) void k_dec1_out(
    const float* __restrict__ G, const float* __restrict__ dw1,
    const float* __restrict__ du1, const float* __restrict__ db1,
    const float* __restrict__ ow, float* __restrict__ out) {
    const int tid = threadIdx.x, wave = tid >> 6, lane = tid & 63;
    const int rA = blockIdx.x * 8 + wave * 2, rB = rA + 1;
    __shared__ float sh[4][TSTEPS][2];

    const float4* wrA = (const float4*)(dw1 + rA * HID);
    const float4* wrB = (const float4*)(dw1 + rB * HID);
    float4 wa[4], wb[4];
#pragma unroll
    for (int k = 0; k < 4; ++k) { wa[k] = wrA[k * 64 + lane]; wb[k] = wrB[k * 64 + lane]; }

    const float uA = du1[rA], bA = db1[rA], o0A = ow[rA], o1A = ow[HID + rA];
    const float uB = du1[rB], bB = db1[rB], o0B = ow[rB], o1B = ow[HID + rB];
    float hA = 0.f, hB = 0.f;

    for (int t = 0; t < TSTEPS; ++t) {
        const float4* gt = (const float4*)(G + t * HID);
        float sA = 0.f, sB = 0.f;
#pragma unroll
        for (int k = 0; k < 4; ++k) {
            float4 g = gt[k * 64 + lane];
            sA = fmaf(wa[k].x, g.x, sA); sA = fmaf(wa[k].y, g.y, sA);
            sA = fmaf(wa[k].z, g.z, sA); sA = fmaf(wa[k].w, g.w, sA);
            sB = fmaf(wb[k].x, g.x, sB); sB = fmaf(wb[k].y, g.y, sB);
            sB = fmaf(wb[k].z, g.z, sB); sB = fmaf(wb[k].w, g.w, sB);
        }
        sA = wred64(sA);
        sB = wred64(sB);
        if (lane == 0) {
            hA = fmaxf(fmaf(uA, hA, sA + bA), 0.f);
            hB = fmaxf(fmaf(uB, hB, sB + bB), 0.f);
            sh[wave][t][0] = fmaf(o0A, hA, o0B * hB);
            sh[wave][t][1] = fmaf(o1A, hA, o1B * hB);
        }
    }
    __syncthreads();
    if (tid < 2 * TSTEPS) {
        const int t = tid >> 1, j = tid & 1;
        float v = sh[0][t][j] + sh[1][t][j] + sh[2][t][j] + sh[3][t][j];
        atomicAdd(&out[t * 2 + j], v);
    }
}

extern "C" void kernel_launch(void* const* d_in, const int* in_sizes, int n_in,
                              void* d_out, int out_size, void* d_ws, size_t ws_size,
                              hipStream_t stream) {
    const float* x      = (const float*)d_in[0];
    const float* enc_w0 = (const float*)d_in[1];
    // d_in[2] = enc_u0 — provably unused (encoder only matters at t=0)
    const float* enc_b0 = (const float*)d_in[3];
    const float* enc_w1 = (const float*)d_in[4];
    // d_in[5] = enc_u1 — unused
    const float* enc_b1 = (const float*)d_in[6];
    const float* dec_w0 = (const float*)d_in[7];
    const float* dec_u0 = (const float*)d_in[8];
    const float* dec_b0 = (const float*)d_in[9];
    const float* dec_w1 = (const float*)d_in[10];
    const float* dec_u1 = (const float*)d_in[11];
    const float* dec_b1 = (const float*)d_in[12];
    const float* out_w  = (const float*)d_in[13];
    const float* out_b  = (const float*)d_in[14];
    float* out = (float*)d_out;

    float* ws    = (float*)d_ws;
    float* last0 = ws;          // 1024 floats
    float* G     = ws + HID;    // 20*1024 floats

    k_enc<<<256, 256, 0, stream>>>(x, enc_w0, enc_b0, enc_w1, enc_b1,
                                   out_b, last0, out);
    k_dec0<<<256, 256, 0, stream>>>(last0, dec_w0, dec_u0, dec_b0, G);
    k_dec1_out<<<128, 256, 0, stream>>>(G, dec_w1, dec_u1, dec_b1, out_w, out);
}

// Round 4
// 102.253 us; speedup vs baseline: 2.5928x; 1.0732x over previous
//
#include <hip/hip_runtime.h>

// IndRNN net, algebraically collapsed (verified exact, absmax=0.0 in R1-R3):
// predict uses only decoder-batch 0 => last[0] = y_enc1[t=0, b=4095] =>
// encoder needed only at (t=0, b=4095); recurrent u terms vanish at t=0.
// 3-kernel chain (R2 showed in-kernel grid barriers cost ~60us/barrier from
// cross-XCD L2 maintenance; R3 showed a ~90us harness floor: 268MB ws poison
// fill ~40us + input restores). R4: cut K3's serial critical path 4x by
// splitting the 20 independent matvec reductions across the 4 waves; only
// the 20-step scalar scan stays serial (it's ~40 cycles).

#define HID 1024
#define TSTEPS 20

__device__ __forceinline__ float wred64(float v) {
#pragma unroll
    for (int off = 32; off > 0; off >>= 1) v += __shfl_down(v, off, 64);
    return v;  // lane 0 holds the sum
}

// K1: v0 = relu(ew0 @ x[0,4095] + eb0); last0 = relu(ew1 @ v0 + eb1)
// Also seeds out[t][j] = ob[j] (K3 accumulates into it via atomicAdd;
// stream order K1 -> K3 guarantees the seed lands first).
__global__ __launch_bounds__(256) void k_enc(
    const float* __restrict__ x, const float* __restrict__ ew0,
    const float* __restrict__ eb0, const float* __restrict__ ew1,
    const float* __restrict__ eb1, const float* __restrict__ ob,
    float* __restrict__ last0, float* __restrict__ out) {
    const int tid = threadIdx.x, wave = tid >> 6, lane = tid & 63;
    __shared__ float v0s[HID];

    if (blockIdx.x == 0 && tid < 2 * TSTEPS) out[tid] = ob[tid & 1];

    const float x0 = x[8190], x1 = x[8191];  // x[t=0, b=4095, :]
#pragma unroll
    for (int i = tid; i < HID / 2; i += 256) {
        float4 w4 = ((const float4*)ew0)[i];   // rows 2i, 2i+1 (2 floats each)
        float2 e2 = ((const float2*)eb0)[i];
        v0s[2 * i + 0] = fmaxf(fmaf(w4.x, x0, fmaf(w4.y, x1, e2.x)), 0.f);
        v0s[2 * i + 1] = fmaxf(fmaf(w4.z, x0, fmaf(w4.w, x1, e2.y)), 0.f);
    }
    __syncthreads();

    const int r = blockIdx.x * 4 + wave;           // wave per output row
    const float4* wrow = (const float4*)(ew1 + r * HID);
    const float4* v4 = (const float4*)v0s;
    float s = 0.f;
#pragma unroll
    for (int k = 0; k < 4; ++k) {                   // contiguous 1KB/instr
        float4 w = wrow[k * 64 + lane], v = v4[k * 64 + lane];
        s = fmaf(w.x, v.x, s); s = fmaf(w.y, v.y, s);
        s = fmaf(w.z, v.z, s); s = fmaf(w.w, v.w, s);
    }
    s = wred64(s);
    if (lane == 0) last0[r] = fmaxf(s + eb1[r], 0.f);
}

// K2: p = dw0 @ last0 + db0; G[t][h] = scan relu(p + u0*g)
__global__ __launch_bounds__(256) void k_dec0(
    const float* __restrict__ last0, const float* __restrict__ dw0,
    const float* __restrict__ du0, const float* __restrict__ db0,
    float* __restrict__ G) {
    const int tid = threadIdx.x, wave = tid >> 6, lane = tid & 63;
    __shared__ float l0[HID];
    ((float4*)l0)[tid] = ((const float4*)last0)[tid];
    __syncthreads();

    const int r = blockIdx.x * 4 + wave;
    const float4* wrow = (const float4*)(dw0 + r * HID);
    const float4* v4 = (const float4*)l0;
    float s = 0.f;
#pragma unroll
    for (int k = 0; k < 4; ++k) {
        float4 w = wrow[k * 64 + lane], v = v4[k * 64 + lane];
        s = fmaf(w.x, v.x, s); s = fmaf(w.y, v.y, s);
        s = fmaf(w.z, v.z, s); s = fmaf(w.w, v.w, s);
    }
    s = wred64(s);
    if (lane == 0) {
        const float p = s + db0[r], uu = du0[r];
        float g = 0.f;
#pragma unroll
        for (int t = 0; t < TSTEPS; ++t) {
            g = fmaxf(fmaf(uu, g, p), 0.f);
            G[t * HID + r] = g;
        }
    }
}

// K3: Q[t] = dw1 @ G[t] + db1; H1[t] = scan relu(q + u1*h);
// out[t][j] += ow[j] . H1[t]  (per-block partials + atomicAdd).
// 256 blocks x 4 rows; the 20 independent reductions are split across the
// 4 waves (wave w does t = w, w+4..w+16 -> 5 serial rounds, not 20); only
// the trivial 20-step scan per row is serial.
__global__ __launch_bounds__(256) void k_dec1_out(
    const float* __restrict__ G, const float* __restrict__ dw1,
    const float* __restrict__ du1, const float* __restrict__ db1,
    const float* __restrict__ ow, float* __restrict__ out) {
    const int tid = threadIdx.x, wave = tid >> 6, lane = tid & 63;
    const int r0 = blockIdx.x * 4;
    __shared__ float qs[TSTEPS][4];   // Q[t][row]
    __shared__ float hs[TSTEPS][4];   // H1[t][row]

    // every wave holds all 4 rows' weight chunks (16 KB/block, L1-shared)
    float4 w[4][4];
#pragma unroll
    for (int r = 0; r < 4; ++r) {
        const float4* wr = (const float4*)(dw1 + (r0 + r) * HID);
#pragma unroll
        for (int k = 0; k < 4; ++k) w[r][k] = wr[k * 64 + lane];
    }

#pragma unroll
    for (int ti = 0; ti < 5; ++ti) {
        const int t = wave + ti * 4;
        const float4* gt = (const float4*)(G + t * HID);
        float4 g[4];
#pragma unroll
        for (int k = 0; k < 4; ++k) g[k] = gt[k * 64 + lane];
        float s[4] = {0.f, 0.f, 0.f, 0.f};
#pragma unroll
        for (int r = 0; r < 4; ++r)
#pragma unroll
            for (int k = 0; k < 4; ++k) {
                s[r] = fmaf(w[r][k].x, g[k].x, s[r]);
                s[r] = fmaf(w[r][k].y, g[k].y, s[r]);
                s[r] = fmaf(w[r][k].z, g[k].z, s[r]);
                s[r] = fmaf(w[r][k].w, g[k].w, s[r]);
            }
#pragma unroll
        for (int off = 32; off > 0; off >>= 1) {
            s[0] += __shfl_down(s[0], off, 64);
            s[1] += __shfl_down(s[1], off, 64);
            s[2] += __shfl_down(s[2], off, 64);
            s[3] += __shfl_down(s[3], off, 64);
        }
        if (lane == 0) {
            qs[t][0] = s[0]; qs[t][1] = s[1];
            qs[t][2] = s[2]; qs[t][3] = s[3];
        }
    }
    __syncthreads();

    if (tid < 4) {                       // 20-step scan per row (serial, tiny)
        const int r = r0 + tid;
        const float uu = du1[r], bb = db1[r];
        float h = 0.f;
#pragma unroll
        for (int t = 0; t < TSTEPS; ++t) {
            h = fmaxf(fmaf(uu, h, qs[t][tid] + bb), 0.f);
            hs[t][tid] = h;
        }
    }
    __syncthreads();

    if (tid < 2 * TSTEPS) {              // output partials: 40 threads
        const int t = tid >> 1, j = tid & 1;
        const float* owj = ow + j * HID + r0;
        float p = owj[0] * hs[t][0] + owj[1] * hs[t][1]
                + owj[2] * hs[t][2] + owj[3] * hs[t][3];
        atomicAdd(&out[t * 2 + j], p);
    }
}

extern "C" void kernel_launch(void* const* d_in, const int* in_sizes, int n_in,
                              void* d_out, int out_size, void* d_ws, size_t ws_size,
                              hipStream_t stream) {
    const float* x      = (const float*)d_in[0];
    const float* enc_w0 = (const float*)d_in[1];
    // d_in[2] = enc_u0 — provably unused (encoder only matters at t=0)
    const float* enc_b0 = (const float*)d_in[3];
    const float* enc_w1 = (const float*)d_in[4];
    // d_in[5] = enc_u1 — unused
    const float* enc_b1 = (const float*)d_in[6];
    const float* dec_w0 = (const float*)d_in[7];
    const float* dec_u0 = (const float*)d_in[8];
    const float* dec_b0 = (const float*)d_in[9];
    const float* dec_w1 = (const float*)d_in[10];
    const float* dec_u1 = (const float*)d_in[11];
    const float* dec_b1 = (const float*)d_in[12];
    const float* out_w  = (const float*)d_in[13];
    const float* out_b  = (const float*)d_in[14];
    float* out = (float*)d_out;

    float* ws    = (float*)d_ws;
    float* last0 = ws;          // 1024 floats
    float* G     = ws + HID;    // 20*1024 floats

    k_enc<<<256, 256, 0, stream>>>(x, enc_w0, enc_b0, enc_w1, enc_b1,
                                   out_b, last0, out);
    k_dec0<<<256, 256, 0, stream>>>(last0, dec_w0, dec_u0, dec_b0, G);
    k_dec1_out<<<256, 256, 0, stream>>>(G, dec_w1, dec_u1, dec_b1, out_w, out);
}